// Round 2
// baseline (1502.822 us; speedup 1.0000x reference)
//
#include <hip/hip_runtime.h>
#include <hip/hip_bf16.h>

#define Vn 25000
#define En 100000
#define NODE_IN 74
#define EDGE_IN 12
#define OUTD 64
#define EHID 128
#define NUM_STEPS 6

typedef __attribute__((ext_vector_type(8))) short short8;
typedef __attribute__((ext_vector_type(4))) float floatx4;

__device__ __forceinline__ short f2bfbits(float x) {
  union { float fv; unsigned u; } c; c.fv = x;
  unsigned r = (c.u + 0x7fffu + ((c.u >> 16) & 1u)) >> 16;
  return (short)r;
}

// h[v,o] = relu(node[v,:] @ Wp + bp)   [V,74]@[74,64]  (all fp32)
__global__ void proj_kernel(const float* __restrict__ node,
                            const float* __restrict__ Wp,
                            const float* __restrict__ bp,
                            float* __restrict__ h) {
  __shared__ float nf[NODE_IN];
  int v = blockIdx.x;
  int o = threadIdx.x;  // 64
  for (int i = o; i < NODE_IN; i += 64) nf[i] = node[(size_t)v * NODE_IN + i];
  __syncthreads();
  float acc = bp[o];
  for (int i = 0; i < NODE_IN; ++i) acc = fmaf(nf[i], Wp[i * OUTD + o], acc);
  h[(size_t)v * OUTD + o] = fmaxf(acc, 0.0f);
}

// f[e,k] = relu(edge[e,:] @ We1 + be1)   [E,12]@[12,128] fp32, stored bf16
__global__ void edge_kernel(const float* __restrict__ ef,
                            const float* __restrict__ We1,
                            const float* __restrict__ be1,
                            __hip_bfloat16* __restrict__ f) {
  __shared__ float es[EDGE_IN];
  int e = blockIdx.x;
  int k = threadIdx.x;  // 128
  if (k < EDGE_IN) es[k] = ef[(size_t)e * EDGE_IN + k];
  __syncthreads();
  float acc = be1[k];
  for (int j = 0; j < EDGE_IN; ++j) acc = fmaf(es[j], We1[j * EHID + k], acc);
  f[(size_t)e * EHID + k] = __float2bfloat16(fmaxf(acc, 0.0f));
}

// w2r[(i*64+o)*128 + k] = bf16(We2[k*4096 + i*64 + o])  (B-operand layout: contiguous k per col)
__global__ void w2r_kernel(const float* __restrict__ We2,
                           __hip_bfloat16* __restrict__ w2r) {
  int g = blockIdx.x * 256 + threadIdx.x;  // < 64*64*128
  int col = g >> 7;
  int k = g & 127;
  w2r[g] = __float2bfloat16(We2[(size_t)k * (OUTD * OUTD) + col]);
}

// Fused per-step message kernel: per 64-edge tile, for i in 0..63:
//   C[e,o] = F[e,:] @ We2[:, i*64+o]  (MFMA),  msg[e,o] += h[src[e],i] * C[e,o]
// (+ be2 mini-GEMM term), then atomic scatter to agg[dst].
__global__ __launch_bounds__(256) void msg_kernel(
    const float* __restrict__ h,
    const __hip_bfloat16* __restrict__ f,
    const __hip_bfloat16* __restrict__ w2r,
    const int* __restrict__ src,
    const int* __restrict__ dst,
    const float* __restrict__ be2,
    float* __restrict__ agg) {
  __shared__ float h_t[64 * 68];          // [i][e_local], pad 68 keeps 16B alignment, conflict-free
  __shared__ unsigned short be2s[4096];   // be2 as bf16 bits
  __shared__ int s_dst[64];

  const int tid = threadIdx.x;
  const int wv = tid >> 6;        // wave 0..3 -> col stripe
  const int lane = tid & 63;
  const int quad = lane >> 4;
  const int l15 = lane & 15;
  const int e0 = blockIdx.x * 64;

  if (tid < 64) {
    int e = e0 + tid;
    s_dst[tid] = (e < En) ? dst[e] : -1;
  }
  {
    int e = tid & 63;
    int ib = tid >> 6;  // i-block 0..3 (16 i's each)
    int eg = e0 + e;
    int sv = (eg < En) ? src[eg] : 0;
    const float4* hp = reinterpret_cast<const float4*>(h + (size_t)sv * OUTD + ib * 16);
    for (int c = 0; c < 4; ++c) {
      float4 val = hp[c];
      int ib4 = ib * 16 + c * 4;
      h_t[(ib4 + 0) * 68 + e] = val.x;
      h_t[(ib4 + 1) * 68 + e] = val.y;
      h_t[(ib4 + 2) * 68 + e] = val.z;
      h_t[(ib4 + 3) * 68 + e] = val.w;
    }
  }
  for (int idx = tid; idx < 4096; idx += 256)
    be2s[idx] = (unsigned short)f2bfbits(be2[idx]);
  __syncthreads();

  // A-fragments: F rows for all 4 row-tiles x 4 K-steps, constant across i-loop.
  // A[m=lane&15][k = s*32 + quad*8 + j]
  short8 afr[4][4];
  for (int t = 0; t < 4; ++t) {
    int e = e0 + t * 16 + l15;
    if (e >= En) e = En - 1;  // clamped rows' outputs are suppressed at scatter
    const short* fr = reinterpret_cast<const short*>(f) + (size_t)e * EHID + quad * 8;
    for (int s = 0; s < 4; ++s)
      afr[t][s] = *reinterpret_cast<const short8*>(fr + s * 32);
  }

  const short* w2b = reinterpret_cast<const short*>(w2r) +
                     (size_t)(wv * 16 + l15) * EHID + quad * 8;

  floatx4 msgacc[4];
  const floatx4 zero4 = (floatx4){0.f, 0.f, 0.f, 0.f};
  for (int t = 0; t < 4; ++t) msgacc[t] = zero4;

  // B-fragments for i=0, then software-prefetch i+1 each iteration.
  short8 bc[4];
  for (int s = 0; s < 4; ++s) bc[s] = *reinterpret_cast<const short8*>(w2b + s * 32);

  for (int i = 0; i < 64; ++i) {
    int inx = (i < 63) ? (i + 1) : 63;
    const short* wp = w2b + (size_t)inx * (64 * EHID);
    short8 bn[4];
    for (int s = 0; s < 4; ++s) bn[s] = *reinterpret_cast<const short8*>(wp + s * 32);

    floatx4 hv[4];
    for (int t = 0; t < 4; ++t)
      hv[t] = *reinterpret_cast<const floatx4*>(&h_t[i * 68 + t * 16 + quad * 4]);

    for (int t = 0; t < 4; ++t) {
      floatx4 c = __builtin_amdgcn_mfma_f32_16x16x32_bf16(afr[t][0], bc[0], zero4, 0, 0, 0);
      c = __builtin_amdgcn_mfma_f32_16x16x32_bf16(afr[t][1], bc[1], c, 0, 0, 0);
      c = __builtin_amdgcn_mfma_f32_16x16x32_bf16(afr[t][2], bc[2], c, 0, 0, 0);
      c = __builtin_amdgcn_mfma_f32_16x16x32_bf16(afr[t][3], bc[3], c, 0, 0, 0);
      msgacc[t] += c * hv[t];  // per-row h scale, fp32
    }
    for (int s = 0; s < 4; ++s) bc[s] = bn[s];
  }

  // be2 contribution: msg[e,o] += sum_i h[src,i] * be2[i*64+o]  (K=64 mini-GEMM; exact 0 here)
  {
    short8 bb[2];
    for (int s = 0; s < 2; ++s) {
      short8 v;
      for (int j = 0; j < 8; ++j)
        v[j] = (short)be2s[(s * 32 + quad * 8 + j) * 64 + wv * 16 + l15];
      bb[s] = v;
    }
    for (int t = 0; t < 4; ++t) {
      short8 ha[2];
      for (int s = 0; s < 2; ++s)
        for (int j = 0; j < 8; ++j)
          ha[s][j] = f2bfbits(h_t[(s * 32 + quad * 8 + j) * 68 + t * 16 + l15]);
      msgacc[t] = __builtin_amdgcn_mfma_f32_16x16x32_bf16(ha[0], bb[0], msgacc[t], 0, 0, 0);
      msgacc[t] = __builtin_amdgcn_mfma_f32_16x16x32_bf16(ha[1], bb[1], msgacc[t], 0, 0, 0);
    }
  }

  // scatter: C/D layout col=lane&15, row=quad*4+reg
  int col = wv * 16 + l15;
  for (int t = 0; t < 4; ++t) {
    int rb = t * 16 + quad * 4;
    for (int r = 0; r < 4; ++r) {
      int d = s_dst[rb + r];
      if (d >= 0) atomicAdd(&agg[(size_t)d * OUTD + col], msgacc[t][r]);
    }
  }
}

// h_out = relu(agg + bias); re-zero agg for next step; last step also writes fp32 d_out
__global__ void update_kernel(float* __restrict__ agg,
                              const float* __restrict__ bias,
                              float* __restrict__ hout,
                              float* __restrict__ dout, int last) {
  int g = blockIdx.x * 256 + threadIdx.x;
  if (g >= Vn * OUTD) return;
  float v = agg[g];
  agg[g] = 0.0f;
  float r = fmaxf(v + bias[g & 63], 0.0f);
  hout[g] = r;
  if (last) dout[g] = r;
}

extern "C" void kernel_launch(void* const* d_in, const int* in_sizes, int n_in,
                              void* d_out, int out_size, void* d_ws, size_t ws_size,
                              hipStream_t stream) {
  const float* node = (const float*)d_in[0];
  const float* edge = (const float*)d_in[1];
  const int* src = (const int*)d_in[2];
  const int* dst = (const int*)d_in[3];
  const float* Wp   = (const float*)d_in[4];
  const float* bp   = (const float*)d_in[5];
  const float* We1  = (const float*)d_in[6];
  const float* be1  = (const float*)d_in[7];
  const float* We2  = (const float*)d_in[8];
  const float* be2  = (const float*)d_in[9];
  const float* bias = (const float*)d_in[10];
  float* out = (float*)d_out;

  char* ws = (char*)d_ws;
  float* agg = (float*)(ws);                              // 6,400,000 B
  float* h_a = (float*)(ws + 6400000);                    // 6,400,000 B
  float* h_b = (float*)(ws + 12800000);                   // 6,400,000 B
  __hip_bfloat16* f   = (__hip_bfloat16*)(ws + 19200000); // 25,600,000 B
  __hip_bfloat16* w2r = (__hip_bfloat16*)(ws + 44800000); // 1,048,576 B

  hipMemsetAsync(agg, 0, (size_t)Vn * OUTD * sizeof(float), stream);
  proj_kernel<<<Vn, 64, 0, stream>>>(node, Wp, bp, h_a);
  edge_kernel<<<En, 128, 0, stream>>>(edge, We1, be1, f);
  w2r_kernel<<<(OUTD * OUTD * EHID) / 256, 256, 0, stream>>>(We2, w2r);

  float* hin = h_a;
  float* hout = h_b;
  for (int s = 0; s < NUM_STEPS; ++s) {
    msg_kernel<<<(En + 63) / 64, 256, 0, stream>>>(hin, f, w2r, src, dst, be2, agg);
    update_kernel<<<(Vn * OUTD + 255) / 256, 256, 0, stream>>>(
        agg, bias, hout, out, s == NUM_STEPS - 1);
    float* t = hin; hin = hout; hout = t;
  }
}

// Round 3
// 960.865 us; speedup vs baseline: 1.5640x; 1.5640x over previous
//
#include <hip/hip_runtime.h>
#include <hip/hip_bf16.h>

#define Vn 25000
#define En 100000
#define NODE_IN 74
#define EDGE_IN 12
#define OUTD 64
#define EHID 128
#define NUM_STEPS 6

typedef __attribute__((ext_vector_type(8))) short short8;
typedef __attribute__((ext_vector_type(4))) float floatx4;

__device__ __forceinline__ short f2bfbits(float x) {
  union { float fv; unsigned u; } c; c.fv = x;
  unsigned r = (c.u + 0x7fffu + ((c.u >> 16) & 1u)) >> 16;
  return (short)r;
}

// h[v,o] = relu(node[v,:] @ Wp + bp)   [V,74]@[74,64]  (all fp32)
__global__ void proj_kernel(const float* __restrict__ node,
                            const float* __restrict__ Wp,
                            const float* __restrict__ bp,
                            float* __restrict__ h) {
  __shared__ float nf[NODE_IN];
  int v = blockIdx.x;
  int o = threadIdx.x;  // 64
  for (int i = o; i < NODE_IN; i += 64) nf[i] = node[(size_t)v * NODE_IN + i];
  __syncthreads();
  float acc = bp[o];
  for (int i = 0; i < NODE_IN; ++i) acc = fmaf(nf[i], Wp[i * OUTD + o], acc);
  h[(size_t)v * OUTD + o] = fmaxf(acc, 0.0f);
}

// f[e,k] = relu(edge[e,:] @ We1 + be1)   [E,12]@[12,128] fp32, stored bf16
__global__ void edge_kernel(const float* __restrict__ ef,
                            const float* __restrict__ We1,
                            const float* __restrict__ be1,
                            __hip_bfloat16* __restrict__ f) {
  __shared__ float es[EDGE_IN];
  int e = blockIdx.x;
  int k = threadIdx.x;  // 128
  if (k < EDGE_IN) es[k] = ef[(size_t)e * EDGE_IN + k];
  __syncthreads();
  float acc = be1[k];
  for (int j = 0; j < EDGE_IN; ++j) acc = fmaf(es[j], We1[j * EHID + k], acc);
  f[(size_t)e * EHID + k] = __float2bfloat16(fmaxf(acc, 0.0f));
}

// Wave-coalesced B layout: w2s element at
//   g = ((((i*4 + wv)*4 + s)*16 + l15)*4 + quad)*8 + j
// holds bf16(We2[k = s*32+quad*8+j][col = i*64 + wv*16 + l15]).
// A wave's (s,i) fragment load is then one contiguous 1 KB transaction.
__global__ void w2r_kernel(const float* __restrict__ We2,
                           __hip_bfloat16* __restrict__ w2s) {
  int g = blockIdx.x * 256 + threadIdx.x;  // < 64*64*128 = 524288
  int j = g & 7;
  int quad = (g >> 3) & 3;
  int l15 = (g >> 5) & 15;
  int s = (g >> 9) & 3;
  int wv = (g >> 11) & 3;
  int i = g >> 13;
  int k = s * 32 + quad * 8 + j;
  int col = i * 64 + wv * 16 + l15;
  w2s[g] = __float2bfloat16(We2[(size_t)k * (OUTD * OUTD) + col]);
}

// Fused per-step message kernel: per 64-edge tile, for i in 0..63:
//   C[e,o] = F[e,:] @ We2[:, i*64+o]  (MFMA),  msg[e,o] += h[src[e],i] * C[e,o]
// (+ be2 mini-GEMM term), then atomic scatter to agg[dst].
__global__ __launch_bounds__(256) void msg_kernel(
    const float* __restrict__ h,
    const __hip_bfloat16* __restrict__ f,
    const __hip_bfloat16* __restrict__ w2s,
    const int* __restrict__ src,
    const int* __restrict__ dst,
    const float* __restrict__ be2,
    float* __restrict__ agg) {
  __shared__ float h_t[64 * 68];   // [i][e_local], pad 68 keeps 16B alignment
  __shared__ int s_dst[64];

  const int tid = threadIdx.x;
  const int wv = tid >> 6;        // wave 0..3 -> col stripe
  const int lane = tid & 63;
  const int quad = lane >> 4;
  const int l15 = lane & 15;
  const int e0 = blockIdx.x * 64;

  if (tid < 64) {
    int e = e0 + tid;
    s_dst[tid] = (e < En) ? dst[e] : -1;
  }
  {
    int e = tid & 63;
    int ib = tid >> 6;  // i-block 0..3 (16 i's each)
    int eg = e0 + e;
    int sv = (eg < En) ? src[eg] : 0;
    const float4* hp = reinterpret_cast<const float4*>(h + (size_t)sv * OUTD + ib * 16);
    for (int c = 0; c < 4; ++c) {
      float4 val = hp[c];
      int ib4 = ib * 16 + c * 4;
      h_t[(ib4 + 0) * 68 + e] = val.x;
      h_t[(ib4 + 1) * 68 + e] = val.y;
      h_t[(ib4 + 2) * 68 + e] = val.z;
      h_t[(ib4 + 3) * 68 + e] = val.w;
    }
  }
  __syncthreads();

  // A-fragments: F rows for all 4 row-tiles x 4 K-steps, constant across i-loop.
  // A[m=lane&15][k = s*32 + quad*8 + j]
  short8 afr[4][4];
  for (int t = 0; t < 4; ++t) {
    int e = e0 + t * 16 + l15;
    if (e >= En) e = En - 1;  // clamped rows' outputs are suppressed at scatter
    const short* fr = reinterpret_cast<const short*>(f) + (size_t)e * EHID + quad * 8;
    for (int s = 0; s < 4; ++s)
      afr[t][s] = *reinterpret_cast<const short8*>(fr + s * 32);
  }

  // per-wave/lane base into the coalesced B layout
  const short* w2b = reinterpret_cast<const short*>(w2s) +
                     wv * 2048 + l15 * 32 + quad * 8;

#define LOADB(dstv, ii)                                                     \
  {                                                                         \
    const short* p_ = w2b + (size_t)(ii) * 8192;                            \
    dstv[0] = *reinterpret_cast<const short8*>(p_);                         \
    dstv[1] = *reinterpret_cast<const short8*>(p_ + 512);                   \
    dstv[2] = *reinterpret_cast<const short8*>(p_ + 1024);                  \
    dstv[3] = *reinterpret_cast<const short8*>(p_ + 1536);                  \
  }

  floatx4 msgacc[4];
  const floatx4 zero4 = (floatx4){0.f, 0.f, 0.f, 0.f};
  for (int t = 0; t < 4; ++t) msgacc[t] = zero4;

  short8 ba[4], bb[4];
  LOADB(ba, 0);
  LOADB(bb, 1);

#define BODY(iv, breg)                                                         \
  {                                                                            \
    floatx4 hv[4];                                                             \
    for (int t = 0; t < 4; ++t)                                                \
      hv[t] = *reinterpret_cast<const floatx4*>(&h_t[(iv) * 68 + t * 16 + quad * 4]); \
    for (int t = 0; t < 4; ++t) {                                              \
      floatx4 c = __builtin_amdgcn_mfma_f32_16x16x32_bf16(afr[t][0], breg[0], zero4, 0, 0, 0); \
      c = __builtin_amdgcn_mfma_f32_16x16x32_bf16(afr[t][1], breg[1], c, 0, 0, 0); \
      c = __builtin_amdgcn_mfma_f32_16x16x32_bf16(afr[t][2], breg[2], c, 0, 0, 0); \
      c = __builtin_amdgcn_mfma_f32_16x16x32_bf16(afr[t][3], breg[3], c, 0, 0, 0); \
      msgacc[t] += c * hv[t];                                                  \
    }                                                                          \
  }

  for (int ii = 0; ii < 32; ++ii) {
    int i0 = 2 * ii;
    BODY(i0, ba);
    {
      int inx = (i0 + 2 < 64) ? i0 + 2 : 63;
      LOADB(ba, inx);
    }
    BODY(i0 + 1, bb);
    {
      int inx = (i0 + 3 < 64) ? i0 + 3 : 63;
      LOADB(bb, inx);
    }
  }

  // be2 contribution: msg[e,o] += sum_i h[src,i] * be2[i*64+o]  (K=64 mini-GEMM; exact 0 here)
  {
    short8 b2f8[2];
    for (int s = 0; s < 2; ++s) {
      short8 v;
      for (int j = 0; j < 8; ++j)
        v[j] = f2bfbits(be2[(s * 32 + quad * 8 + j) * 64 + wv * 16 + l15]);
      b2f8[s] = v;
    }
    for (int t = 0; t < 4; ++t) {
      short8 ha[2];
      for (int s = 0; s < 2; ++s)
        for (int j = 0; j < 8; ++j)
          ha[s][j] = f2bfbits(h_t[(s * 32 + quad * 8 + j) * 68 + t * 16 + l15]);
      msgacc[t] = __builtin_amdgcn_mfma_f32_16x16x32_bf16(ha[0], b2f8[0], msgacc[t], 0, 0, 0);
      msgacc[t] = __builtin_amdgcn_mfma_f32_16x16x32_bf16(ha[1], b2f8[1], msgacc[t], 0, 0, 0);
    }
  }

  // scatter: C/D layout col=lane&15, row=quad*4+reg
  int col = wv * 16 + l15;
  for (int t = 0; t < 4; ++t) {
    int rb = t * 16 + quad * 4;
    for (int r = 0; r < 4; ++r) {
      int d = s_dst[rb + r];
      if (d >= 0) atomicAdd(&agg[(size_t)d * OUTD + col], msgacc[t][r]);
    }
  }
}

// h_out = relu(agg + bias); re-zero agg for next step; last step also writes fp32 d_out
__global__ void update_kernel(float* __restrict__ agg,
                              const float* __restrict__ bias,
                              float* __restrict__ hout,
                              float* __restrict__ dout, int last) {
  int g = blockIdx.x * 256 + threadIdx.x;
  if (g >= Vn * OUTD) return;
  float v = agg[g];
  agg[g] = 0.0f;
  float r = fmaxf(v + bias[g & 63], 0.0f);
  hout[g] = r;
  if (last) dout[g] = r;
}

extern "C" void kernel_launch(void* const* d_in, const int* in_sizes, int n_in,
                              void* d_out, int out_size, void* d_ws, size_t ws_size,
                              hipStream_t stream) {
  const float* node = (const float*)d_in[0];
  const float* edge = (const float*)d_in[1];
  const int* src = (const int*)d_in[2];
  const int* dst = (const int*)d_in[3];
  const float* Wp   = (const float*)d_in[4];
  const float* bp   = (const float*)d_in[5];
  const float* We1  = (const float*)d_in[6];
  const float* be1  = (const float*)d_in[7];
  const float* We2  = (const float*)d_in[8];
  const float* be2  = (const float*)d_in[9];
  const float* bias = (const float*)d_in[10];
  float* out = (float*)d_out;

  char* ws = (char*)d_ws;
  float* agg = (float*)(ws);                              // 6,400,000 B
  float* h_a = (float*)(ws + 6400000);                    // 6,400,000 B
  float* h_b = (float*)(ws + 12800000);                   // 6,400,000 B
  __hip_bfloat16* f   = (__hip_bfloat16*)(ws + 19200000); // 25,600,000 B
  __hip_bfloat16* w2s = (__hip_bfloat16*)(ws + 44800000); // 1,048,576 B

  hipMemsetAsync(agg, 0, (size_t)Vn * OUTD * sizeof(float), stream);
  proj_kernel<<<Vn, 64, 0, stream>>>(node, Wp, bp, h_a);
  edge_kernel<<<En, 128, 0, stream>>>(edge, We1, be1, f);
  w2r_kernel<<<(OUTD * OUTD * EHID) / 256, 256, 0, stream>>>(We2, w2s);

  float* hin = h_a;
  float* hout = h_b;
  for (int s = 0; s < NUM_STEPS; ++s) {
    msg_kernel<<<(En + 63) / 64, 256, 0, stream>>>(hin, f, w2s, src, dst, be2, agg);
    update_kernel<<<(Vn * OUTD + 255) / 256, 256, 0, stream>>>(
        agg, bias, hout, out, s == NUM_STEPS - 1);
    float* t = hin; hin = hout; hout = t;
  }
}